// Round 3
// baseline (674.418 us; speedup 1.0000x reference)
//
#include <hip/hip_runtime.h>

// GraphSAGE 2-layer forward on MI355X.
// Round 13: fix r12's correctness bug. packed[] is only BIN-contiguous
// (128 nodes); within a bin it's in scatter order, so slicing it with
// row_start at 64-node granularity grabbed wrong edges and indexed LDS out
// of range (absmax 322). agg2_bin now processes one FULL bin per block:
// the bin's packed slice IS [row_start[bin*128], row_start[(bin+1)*128]).
// acc[128][44] f32 (23 KB LDS), 512 threads (8 waves) for ~24 waves/CU of
// gather-latency hiding. Structure otherwise = r12: stream packed (dst_local
// <<20|src, randomized in bin), 10 lanes/edge branchless lo/hi uint2 gather,
// ds_add_f32 accumulate, one coalesced RMW writeout * 1/deg. b2 in gemm12.
//   agg_mean: r10 form (fp8 rows, 16 lanes/edge, 4 gathers/lane).
// CSR: deterministic counting sort. GEMM: fused gemm12 (h1 tile in LDS).

typedef __attribute__((ext_vector_type(8))) short bf16x8;
typedef __attribute__((ext_vector_type(4))) float f32x4;
typedef __attribute__((ext_vector_type(2))) float f32x2;

#define BIN_SHIFT 7
#define BIN_SIZE  128
#define NB        256          // scatter blocks (= scan block size!)

#define OFF_ROWSTART (1ull << 20)   // 400 KB
#define OFF_HIST     (2ull << 20)   // 800 KB  hist[bin*NB + blk]
#define OFF_SCAN     (3ull << 20)   // 800 KB  block-local exclusive prefix
#define OFF_BSUMS    (4ull << 20)
#define OFF_BOFFS    ((4ull << 20) + (64ull << 10))
#define OFF_PACKED   (5ull << 20)   // 6.4 MB
#define OFF_CSR      (12ull << 20)  // 6.4 MB
#define OFF_W1T      (19ull << 20)  // 64 KB
#define OFF_W2T      (20ull << 20)  // 20 KB
#define OFF_XB       (21ull << 20)  // 25.6 MB bf16 (gemm12 self-term)
#define OFF_XQ       (47ull << 20)  // 12.8 MB + zero row (fp8, N+1 rows)
#define OFF_AGGB     (61ull << 20)  // 25.6 MB bf16
#define OFF_T2LO     (87ull << 20)  // 6.4 MB (32 bf16/row = 64 B)
#define OFF_T2HI     (94ull << 20)  // 1.6 MB (8 bf16/row = 16 B)
#define T2HI_DELTA   (7u << 20)     // byte offset of t2hi relative to t2lo

static __device__ __forceinline__ unsigned short f2b(float f) {
    unsigned int u = __float_as_uint(f);
    u += 0x7fffu + ((u >> 16) & 1u);   // round-to-nearest-even
    return (unsigned short)(u >> 16);
}
static __device__ __forceinline__ float blo(unsigned int v) { return __uint_as_float(v << 16); }
static __device__ __forceinline__ float bhi(unsigned int v) { return __uint_as_float(v & 0xffff0000u); }

// ------------------------------------------------- CSR via counting sort

__global__ __launch_bounds__(256) void hist_local(
    const int* __restrict__ dst, int* __restrict__ hist, int E, int nbins) {
    __shared__ int h[1024];
    int b = blockIdx.x, t = threadIdx.x;
    for (int i = t; i < nbins; i += 256) h[i] = 0;
    __syncthreads();
    int chunk = (E + NB - 1) / NB;
    int base = b * chunk;
    int lim = min(base + chunk, E);
    for (int e = base + t; e < lim; e += 256)
        atomicAdd(&h[dst[e] >> BIN_SHIFT], 1);
    __syncthreads();
    for (int i = t; i < nbins; i += 256)
        hist[i * NB + b] = h[i];
}

__global__ void scan1(const int* __restrict__ in, int* __restrict__ tmp,
                      int* __restrict__ bsums, int M) {
    __shared__ int s[256];
    int t = threadIdx.x;
    int i = blockIdx.x * 256 + t;
    int v = (i < M) ? in[i] : 0;
    s[t] = v;
    __syncthreads();
    for (int off = 1; off < 256; off <<= 1) {
        int u = (t >= off) ? s[t - off] : 0;
        __syncthreads();
        s[t] += u;
        __syncthreads();
    }
    if (i < M) tmp[i] = s[t] - v;
    if (t == 255) bsums[blockIdx.x] = s[t];
}

__global__ void scan2(const int* __restrict__ bsums, int* __restrict__ boffs, int nb) {
    __shared__ int s[1024];
    int t = threadIdx.x;
    int v = (t < nb) ? bsums[t] : 0;
    s[t] = v;
    __syncthreads();
    for (int off = 1; off < 1024; off <<= 1) {
        int u = (t >= off) ? s[t - off] : 0;
        __syncthreads();
        s[t] += u;
        __syncthreads();
    }
    if (t < nb) boffs[t] = s[t] - v;
}

__global__ __launch_bounds__(256) void scatter_det(
    const int* __restrict__ src, const int* __restrict__ dst,
    const int* __restrict__ tmp, const int* __restrict__ boffs,
    unsigned int* __restrict__ packed, int E, int nbins) {
    __shared__ int cur[1024];
    int b = blockIdx.x, t = threadIdx.x;
    for (int i = t; i < nbins; i += 256) cur[i] = tmp[i * NB + b] + boffs[i];
    __syncthreads();
    int chunk = (E + NB - 1) / NB;
    int base = b * chunk;
    int lim = min(base + chunk, E);
    for (int e = base + t; e < lim; e += 256) {
        int d = dst[e];
        int bin = d >> BIN_SHIFT;
        int pos = atomicAdd(&cur[bin], 1);   // LDS atomic
        packed[pos] = ((unsigned int)(d & (BIN_SIZE - 1)) << 20) | (unsigned int)src[e];
    }
}

__global__ __launch_bounds__(256) void bin_fill(
    const unsigned int* __restrict__ packed, const int* __restrict__ tmp,
    const int* __restrict__ boffs,
    int* __restrict__ row_start, int* __restrict__ csr_src, int N, int nbins, int E) {
    __shared__ int cnt[BIN_SIZE];
    __shared__ int pre[BIN_SIZE];
    __shared__ int ex[BIN_SIZE];
    int b = blockIdx.x;
    int t = threadIdx.x;
    int node0 = b << BIN_SHIFT;
    int beg = tmp[b * NB] + boffs[b];
    int end = (b + 1 < nbins) ? (tmp[(b + 1) * NB] + boffs[b + 1]) : E;

    if (t < BIN_SIZE) cnt[t] = 0;
    __syncthreads();
    for (int i = beg + t; i < end; i += 256)
        atomicAdd(&cnt[packed[i] >> 20], 1);
    __syncthreads();
    if (t < BIN_SIZE) pre[t] = cnt[t];
    __syncthreads();
    for (int off = 1; off < BIN_SIZE; off <<= 1) {
        int u = (t < BIN_SIZE && t >= off) ? pre[t - off] : 0;
        __syncthreads();
        if (t < BIN_SIZE) pre[t] += u;
        __syncthreads();
    }
    if (t < BIN_SIZE) {
        ex[t] = pre[t] - cnt[t];
        int node = node0 + t;
        if (node < N) row_start[node] = beg + ex[t];
        cnt[t] = 0;
    }
    if (b == nbins - 1 && t == 0) row_start[N] = E;
    __syncthreads();
    for (int i = beg + t; i < end; i += 256) {
        unsigned int p = packed[i];
        int dl = p >> 20;
        int s = p & 0xFFFFF;
        int ofs = atomicAdd(&cnt[dl], 1);
        csr_src[beg + ex[dl] + ofs] = s;
    }
}

// ------------------------------------------------------------- prep kernel
// blocks [0, castBlocks): x -> xb (bf16) + xq (fp8 e4m3), 16 dims/thread.
// next 128: W1t transpose; next 80: W2t; last 1: zero row (xq @ N).

__global__ void cast_prep(const float* __restrict__ x,
                          const float* __restrict__ W1s, const float* __restrict__ W1n,
                          const float* __restrict__ W2s, const float* __restrict__ W2n,
                          unsigned short* __restrict__ xb, unsigned char* __restrict__ xq,
                          unsigned short* __restrict__ W1t, unsigned short* __restrict__ W2t,
                          int n16, int castBlocks, int N) {
    int blk = blockIdx.x, t = threadIdx.x;
    if (blk < castBlocks) {
        int i = blk * 256 + t;
        if (i >= n16) return;
        const float4* p = (const float4*)x + (size_t)i * 4;
        float4 v0 = p[0], v1 = p[1], v2 = p[2], v3 = p[3];
        float f[16] = {v0.x, v0.y, v0.z, v0.w, v1.x, v1.y, v1.z, v1.w,
                       v2.x, v2.y, v2.z, v2.w, v3.x, v3.y, v3.z, v3.w};
        unsigned short ob[16];
#pragma unroll
        for (int k = 0; k < 16; k++) ob[k] = f2b(f[k]);
        *(float4*)(xb + (size_t)i * 16) = *(float4*)&ob[0];
        *(float4*)(xb + (size_t)i * 16 + 8) = *(float4*)&ob[8];
        unsigned int w[4];
#pragma unroll
        for (int k = 0; k < 4; k++) {
            int u = __builtin_amdgcn_cvt_pk_fp8_f32(f[4 * k + 0], f[4 * k + 1], 0, false);
            u = __builtin_amdgcn_cvt_pk_fp8_f32(f[4 * k + 2], f[4 * k + 3], u, true);
            w[k] = (unsigned int)u;
        }
        *(uint4*)(xq + (size_t)i * 16) = *(uint4*)w;
    } else if (blk < castBlocks + 128) {
        int c = blk - castBlocks;
        float v = (t < 128) ? W1s[(size_t)t * 128 + c] : W1n[(size_t)(t - 128) * 128 + c];
        W1t[(size_t)c * 256 + t] = f2b(v);
    } else if (blk < castBlocks + 208) {
        if (t < 128) {
            int c = blk - castBlocks - 128;
            float v = (c < 40) ? W2s[(size_t)t * 40 + c] : W2n[(size_t)t * 40 + (c - 40)];
            W2t[(size_t)c * 128 + t] = f2b(v);
        }
    } else {
        // zero row at index N (xq: 128 B) for agg_mean's predicated gathers
        if (t < 32) ((unsigned int*)(xq + (size_t)N * 128))[t] = 0u;
    }
}

// ------------------------------------------------------- aggregation kernels

// One wave per node over fp8 rows (128 B). Quarter q handles edges e+4q+k
// (k=0..3); lane-in-quarter l owns dims [8l, 8l+8) via uint2. Out-of-range
// slots clamp to zero row N -> every iteration issues 4 gathers/lane.
__global__ void agg_mean_fp8(const unsigned char* __restrict__ xq,
                             const int* __restrict__ row_start,
                             const int* __restrict__ csr_src,
                             unsigned short* __restrict__ aggb, int N) {
    int wave = (blockIdx.x * blockDim.x + threadIdx.x) >> 6;
    int lane = threadIdx.x & 63;
    if (wave >= N) return;
    int q = lane >> 4;
    int l = lane & 15;
    int beg = row_start[wave], end = row_start[wave + 1];
    const char* xbase = (const char*)xq;
    unsigned loff = (unsigned)l << 3;

    float a[8];
#pragma unroll
    for (int k = 0; k < 8; k++) a[k] = 0.f;

    for (int e = beg; e < end; e += 16) {
        int eq = e + 4 * q;
        int s[4];
#pragma unroll
        for (int k = 0; k < 4; k++) {
            int ee = eq + k;
            int idx = csr_src[min(ee, end - 1)];
            s[k] = (ee < end) ? idx : N;          // N = zero row
        }
#pragma unroll
        for (int k = 0; k < 4; k++) {
            uint2 v = *(const uint2*)(xbase + (((unsigned)s[k] << 7) + loff));
            f32x2 p0 = __builtin_amdgcn_cvt_pk_f32_fp8(v.x, false);
            f32x2 p1 = __builtin_amdgcn_cvt_pk_f32_fp8(v.x, true);
            f32x2 p2 = __builtin_amdgcn_cvt_pk_f32_fp8(v.y, false);
            f32x2 p3 = __builtin_amdgcn_cvt_pk_f32_fp8(v.y, true);
            a[0] += p0.x; a[1] += p0.y; a[2] += p1.x; a[3] += p1.y;
            a[4] += p2.x; a[5] += p2.y; a[6] += p3.x; a[7] += p3.y;
        }
    }

#pragma unroll
    for (int k = 0; k < 8; k++) {
        a[k] += __shfl_xor(a[k], 16);
        a[k] += __shfl_xor(a[k], 32);
    }
    if (q == 0) {
        float inv = 1.0f / fmaxf((float)(end - beg), 1.0f);
        unsigned int ow[4];
#pragma unroll
        for (int k = 0; k < 4; k++)
            ow[k] = (unsigned int)f2b(a[2 * k] * inv) |
                    ((unsigned int)f2b(a[2 * k + 1] * inv) << 16);
        *(uint4*)((char*)aggb + (((unsigned)wave << 8) + ((unsigned)l << 4))) = *(uint4*)ow;
    }
}

// Layer-2 aggregation, bin-streaming. Block = one FULL 128-node bin; its
// packed slice is exactly [row_start[bin*128], row_start[(bin+1)*128])
// (within-bin order is a permutation -- boundaries match csr coordinates).
// Wave: 6 edges x 10 lanes (lane = eslot*10 + dslot); dslot 0-7 gather uint2
// from t2lo (64 B rows), 8-9 from t2hi (16 B rows) via branchless unified
// voffset = (s << shiftv) + addv off one base pointer. Values ds_add_f32
// into acc[128][44] f32 (dl randomized -> low same-address contention);
// writeout: one coalesced RMW of out (self+b2 from gemm12) * 1/deg.
__global__ __launch_bounds__(512) void agg2_bin(
    const unsigned short* __restrict__ t2lo,
    const unsigned int* __restrict__ packed,
    const int* __restrict__ row_start,
    float* __restrict__ out, int N) {

    __shared__ float accf[128 * 44];
    __shared__ float sinv[128];

    int tid = threadIdx.x;
    int b = blockIdx.x;
    int node0 = b << BIN_SHIFT;              // bin-aligned!

    for (int i = tid; i < 128 * 44; i += 512) accf[i] = 0.f;
    if (tid < 128) {
        int node = node0 + tid;
        int dg = (node < N) ? row_start[node + 1] - row_start[node] : 1;
        sinv[tid] = 1.0f / (float)max(dg, 1);
    }
    int beg = row_start[node0];
    int end = row_start[min(node0 + BIN_SIZE, N)];
    __syncthreads();

    int wave = tid >> 6, lane = tid & 63;
    int eslot = lane / 10;                   // 0..6 (6 = idle lanes 60-63)
    int dslot = lane - eslot * 10;           // 0..9
    bool isLo = (dslot < 8);
    unsigned shiftv = isLo ? 6u : 4u;
    unsigned addv = isLo ? ((unsigned)dslot << 3)
                         : (T2HI_DELTA + ((unsigned)(dslot - 8) << 3));
    bool act = (eslot < 6);
    const char* t2b = (const char*)t2lo;

#pragma unroll 2
    for (int ew = beg + wave * 6; ew < end; ew += 48) {
        int ee = ew + eslot;
        if (act && ee < end) {
            unsigned p = packed[ee];
            int dl = (int)(p >> 20);
            unsigned s = p & 0xFFFFFu;
            uint2 v = *(const uint2*)(t2b + ((s << shiftv) + addv));
            float* ap = accf + dl * 44 + (dslot << 2);
            atomicAdd(ap + 0, blo(v.x));
            atomicAdd(ap + 1, bhi(v.x));
            atomicAdd(ap + 2, blo(v.y));
            atomicAdd(ap + 3, bhi(v.y));
        }
    }
    __syncthreads();

    for (int idx = tid; idx < 128 * 40; idx += 512) {
        int n = idx / 40;
        int d = idx - n * 40;
        int node = node0 + n;
        if (node < N) {
            float* op = out + (size_t)node * 40 + d;
            *op += accf[n * 44 + d] * sinv[n];
        }
    }
}

// --------------------------------------------------------------- fused GEMM
// Phase 1: h1 = relu([xb|aggb] @ W1cat + b1) into LDS (128x136-stride bf16).
// Phase 2: [out_self+b2 | t2lo|t2hi] = h1_tile @ W2cat (W2t in LDS).

__global__ __launch_bounds__(256) void gemm12_mfma(
    const unsigned short* __restrict__ xb, const unsigned short* __restrict__ aggb,
    const unsigned short* __restrict__ W1t, const unsigned short* __restrict__ W2t,
    const float* __restrict__ b1, const float* __restrict__ b2,
    float* __restrict__ out,
    unsigned short* __restrict__ t2lo, unsigned short* __restrict__ t2hi, int N) {

    __shared__ unsigned short As[128 * 40];
    __shared__ unsigned short Bs[128 * 40];
    __shared__ unsigned short Hs[128 * 136];   // h1 tile, +8 pad
    __shared__ unsigned short B2[80 * 136];    // W2t resident

    int tid = threadIdx.x;
    int wave = tid >> 6, lane = tid & 63;
    int row0 = blockIdx.x * 128;
    int m = lane & 15, quad = lane >> 4;

    for (int idx = tid; idx < 1280; idx += 256) {
        int r = idx >> 4, seg = idx & 15;
        *(float4*)&B2[r * 136 + seg * 8] = *(const float4*)(W2t + (size_t)r * 128 + seg * 8);
    }

    f32x4 acc[2][8];
#pragma unroll
    for (int i = 0; i < 2; i++)
#pragma unroll
        for (int j = 0; j < 8; j++) acc[i][j] = (f32x4){0.f, 0.f, 0.f, 0.f};

    for (int k0 = 0; k0 < 256; k0 += 32) {
        __syncthreads();
        {
            int r = tid >> 1, kk = (tid & 1) * 16;
            int row = row0 + r;
            float4 v0 = make_float4(0, 0, 0, 0), v1 = v0;
            if (row < N) {
                const unsigned short* s = (k0 < 128)
                    ? (xb + (size_t)row * 128 + k0 + kk)
                    : (aggb + (size_t)row * 128 + (k0 - 128) + kk);
                const float4* p = (const float4*)s;
                v0 = p[0]; v1 = p[1];
            }
            *(float4*)&As[r * 40 + kk] = v0;
            *(float4*)&As[r * 40 + kk + 8] = v1;
            const float4* q2 = (const float4*)(W1t + (size_t)r * 256 + k0 + kk);
            float4 w0 = q2[0], w1 = q2[1];
            *(float4*)&Bs[r * 40 + kk] = w0;
            *(float4*)&Bs[r * 40 + kk + 8] = w1;
        }
        __syncthreads();

        bf16x8 af0 = *(bf16x8*)&As[(wave * 32 + m) * 40 + quad * 8];
        bf16x8 af1 = *(bf16x8*)&As[(wave * 32 + 16 + m) * 40 + quad * 8];
#pragma unroll
        for (int j = 0; j < 8; j++) {
            bf16x8 bfg = *(bf16x8*)&Bs[(j * 16 + m) * 40 + quad * 8];
            acc[0][j] = __builtin_amdgcn_mfma_f32_16x16x32_bf16(af0, bfg, acc[0][j], 0, 0, 0);
            acc[1][j] = __builtin_amdgcn_mfma_f32_16x16x32_bf16(af1, bfg, acc[1][j], 0, 0, 0);
        }
    }

#pragma unroll
    for (int j = 0; j < 8; j++) {
        int col = j * 16 + m;
        float bias = b1[col];
#pragma unroll
        for (int i = 0; i < 2; i++) {
#pragma unroll
            for (int r = 0; r < 4; r++) {
                int rl = wave * 32 + i * 16 + quad * 4 + r;
                Hs[rl * 136 + col] = f2b(fmaxf(acc[i][j][r] + bias, 0.f));
            }
        }
    }
    __syncthreads();

    f32x4 acc2[2][5];
#pragma unroll
    for (int i = 0; i < 2; i++)
#pragma unroll
        for (int j = 0; j < 5; j++) acc2[i][j] = (f32x4){0.f, 0.f, 0.f, 0.f};

#pragma unroll
    for (int k0 = 0; k0 < 128; k0 += 32) {
        bf16x8 af0 = *(bf16x8*)&Hs[(wave * 32 + m) * 136 + k0 + quad * 8];
        bf16x8 af1 = *(bf16x8*)&Hs[(wave * 32 + 16 + m) * 136 + k0 + quad * 8];
#pragma unroll
        for (int j = 0; j < 5; j++) {
            bf16x8 bfg = *(bf16x8*)&B2[(j * 16 + m) * 136 + k0 + quad * 8];
            acc2[0][j] = __builtin_amdgcn_mfma_f32_16x16x32_bf16(af0, bfg, acc2[0][j], 0, 0, 0);
            acc2[1][j] = __builtin_amdgcn_mfma_f32_16x16x32_bf16(af1, bfg, acc2[1][j], 0, 0, 0);
        }
    }

#pragma unroll
    for (int j = 0; j < 5; j++) {
        int col = j * 16 + m;
        float b2v = (col < 40) ? b2[col] : 0.f;
#pragma unroll
        for (int i = 0; i < 2; i++) {
#pragma unroll
            for (int r = 0; r < 4; r++) {
                int row = row0 + wave * 32 + i * 16 + quad * 4 + r;
                if (row < N) {
                    float v = acc2[i][j][r];
                    if (col < 40) {
                        out[(size_t)row * 40 + col] = v + b2v;
                    } else {
                        int td = col - 40;
                        if (td < 32) t2lo[(size_t)row * 32 + td] = f2b(v);
                        else         t2hi[(size_t)row * 8 + (td - 32)] = f2b(v);
                    }
                }
            }
        }
    }
}

// ------------------------------------------------------------------ launch

extern "C" void kernel_launch(void* const* d_in, const int* in_sizes, int n_in,
                              void* d_out, int out_size, void* d_ws, size_t ws_size,
                              hipStream_t stream) {
    const float* x   = (const float*)d_in[0];
    const int*   src = (const int*)d_in[1];
    const int*   dst = (const int*)d_in[2];
    const float* W1s = (const float*)d_in[3];
    const float* W1n = (const float*)d_in[4];
    const float* b1  = (const float*)d_in[5];
    const float* W2s = (const float*)d_in[6];
    const float* W2n = (const float*)d_in[7];
    const float* b2  = (const float*)d_in[8];
    float* out = (float*)d_out;

    int N = in_sizes[0] / 128;
    int E = in_sizes[1];
    int nbins = (N + BIN_SIZE - 1) / BIN_SIZE;   // 782 for N=100000
    int M = nbins * NB;

    char* ws = (char*)d_ws;
    int*            row_start  = (int*)(ws + OFF_ROWSTART);
    int*            hist       = (int*)(ws + OFF_HIST);
    int*            scanned    = (int*)(ws + OFF_SCAN);
    int*            bsums      = (int*)(ws + OFF_BSUMS);
    int*            boffs      = (int*)(ws + OFF_BOFFS);
    unsigned int*   packed     = (unsigned int*)(ws + OFF_PACKED);
    int*            csr_src    = (int*)(ws + OFF_CSR);
    unsigned short* W1t        = (unsigned short*)(ws + OFF_W1T);
    unsigned short* W2t        = (unsigned short*)(ws + OFF_W2T);
    unsigned short* xb         = (unsigned short*)(ws + OFF_XB);
    unsigned char*  xq         = (unsigned char*)(ws + OFF_XQ);
    unsigned short* aggb       = (unsigned short*)(ws + OFF_AGGB);
    unsigned short* t2lo       = (unsigned short*)(ws + OFF_T2LO);
    unsigned short* t2hi       = (unsigned short*)(ws + OFF_T2HI);

    int scanBlocks = (M + 255) / 256;            // == nbins

    hist_local<<<NB, 256, 0, stream>>>(dst, hist, E, nbins);
    scan1<<<scanBlocks, 256, 0, stream>>>(hist, scanned, bsums, M);
    scan2<<<1, 1024, 0, stream>>>(bsums, boffs, scanBlocks);
    scatter_det<<<NB, 256, 0, stream>>>(src, dst, scanned, boffs, packed, E, nbins);
    bin_fill<<<nbins, 256, 0, stream>>>(packed, scanned, boffs, row_start, csr_src, N, nbins, E);

    int n16 = N * 128 / 16;
    int castBlocks = (n16 + 255) / 256;
    cast_prep<<<castBlocks + 128 + 80 + 1, 256, 0, stream>>>(
        x, W1s, W1n, W2s, W2n, xb, xq, W1t, W2t, n16, castBlocks, N);

    int aggBlocks = (N * 64 + 255) / 256;
    agg_mean_fp8<<<aggBlocks, 256, 0, stream>>>(xq, row_start, csr_src, aggb, N);
    gemm12_mfma<<<(N + 127) / 128, 256, 0, stream>>>(xb, aggb, W1t, W2t, b1, b2, out, t2lo, t2hi, N);

    agg2_bin<<<nbins, 512, 0, stream>>>(t2lo, packed, row_start, out, N);
}

// Round 4
// 286.947 us; speedup vs baseline: 2.3503x; 2.3503x over previous
//
#include <hip/hip_runtime.h>

// GraphSAGE 2-layer forward on MI355X.
// Round 14: revert to the r10 structure (verified 276 us) after three
// falsified branches. r13's post-mortem: bin-streaming with per-dword LDS
// atomics costs ~4 cy per lane-atomic (40 lane-atomics/edge = 64M total ->
// 430 us by itself); register accumulation + 2 shuffles (r10) is strictly
// better. r11: halving the gather working set per XCD halves FETCH but
// doubles per-wave iterations -> 2x time (latency-, not miss-BW-bound).
// Only change vs r10: one-iteration csr_src index PREFETCH in both gather
// kernels (issue next iter's 4 index loads before consuming this iter's
// gathers; clamped addressing makes over-read safe). Pure reorder.
//   agg_mean: fp8 rows, 16 lanes/edge (uint2), 16 edges/iter, 4 gathers/lane.
//   agg2:     same structure over split bf16 t2 (t2lo 64B / t2hi 16B rows).
//   Both: predicated full-issue loop via zero row at index N.
// CSR: deterministic counting sort. GEMM: fused gemm12 (h1 tile in LDS).

typedef __attribute__((ext_vector_type(8))) short bf16x8;
typedef __attribute__((ext_vector_type(4))) float f32x4;
typedef __attribute__((ext_vector_type(2))) float f32x2;

#define BIN_SHIFT 7
#define BIN_SIZE  128
#define NB        256          // scatter blocks (= scan block size!)

#define OFF_ROWSTART (1ull << 20)   // 400 KB
#define OFF_HIST     (2ull << 20)   // 800 KB  hist[bin*NB + blk]
#define OFF_SCAN     (3ull << 20)   // 800 KB  block-local exclusive prefix
#define OFF_BSUMS    (4ull << 20)
#define OFF_BOFFS    ((4ull << 20) + (64ull << 10))
#define OFF_PACKED   (5ull << 20)   // 6.4 MB
#define OFF_CSR      (12ull << 20)  // 6.4 MB
#define OFF_W1T      (19ull << 20)  // 64 KB
#define OFF_W2T      (20ull << 20)  // 20 KB
#define OFF_XB       (21ull << 20)  // 25.6 MB bf16 (gemm12 self-term)
#define OFF_XQ       (47ull << 20)  // 12.8 MB + zero row (fp8, N+1 rows)
#define OFF_AGGB     (61ull << 20)  // 25.6 MB bf16
#define OFF_T2LO     (87ull << 20)  // 6.4 MB + zero row (32 bf16/row)
#define OFF_T2HI     (94ull << 20)  // 1.6 MB + zero row (8 bf16/row)

static __device__ __forceinline__ unsigned short f2b(float f) {
    unsigned int u = __float_as_uint(f);
    u += 0x7fffu + ((u >> 16) & 1u);   // round-to-nearest-even
    return (unsigned short)(u >> 16);
}
static __device__ __forceinline__ float blo(unsigned int v) { return __uint_as_float(v << 16); }
static __device__ __forceinline__ float bhi(unsigned int v) { return __uint_as_float(v & 0xffff0000u); }

// ------------------------------------------------- CSR via counting sort

__global__ __launch_bounds__(256) void hist_local(
    const int* __restrict__ dst, int* __restrict__ hist, int E, int nbins) {
    __shared__ int h[1024];
    int b = blockIdx.x, t = threadIdx.x;
    for (int i = t; i < nbins; i += 256) h[i] = 0;
    __syncthreads();
    int chunk = (E + NB - 1) / NB;
    int base = b * chunk;
    int lim = min(base + chunk, E);
    for (int e = base + t; e < lim; e += 256)
        atomicAdd(&h[dst[e] >> BIN_SHIFT], 1);
    __syncthreads();
    for (int i = t; i < nbins; i += 256)
        hist[i * NB + b] = h[i];
}

__global__ void scan1(const int* __restrict__ in, int* __restrict__ tmp,
                      int* __restrict__ bsums, int M) {
    __shared__ int s[256];
    int t = threadIdx.x;
    int i = blockIdx.x * 256 + t;
    int v = (i < M) ? in[i] : 0;
    s[t] = v;
    __syncthreads();
    for (int off = 1; off < 256; off <<= 1) {
        int u = (t >= off) ? s[t - off] : 0;
        __syncthreads();
        s[t] += u;
        __syncthreads();
    }
    if (i < M) tmp[i] = s[t] - v;
    if (t == 255) bsums[blockIdx.x] = s[t];
}

__global__ void scan2(const int* __restrict__ bsums, int* __restrict__ boffs, int nb) {
    __shared__ int s[1024];
    int t = threadIdx.x;
    int v = (t < nb) ? bsums[t] : 0;
    s[t] = v;
    __syncthreads();
    for (int off = 1; off < 1024; off <<= 1) {
        int u = (t >= off) ? s[t - off] : 0;
        __syncthreads();
        s[t] += u;
        __syncthreads();
    }
    if (t < nb) boffs[t] = s[t] - v;
}

__global__ __launch_bounds__(256) void scatter_det(
    const int* __restrict__ src, const int* __restrict__ dst,
    const int* __restrict__ tmp, const int* __restrict__ boffs,
    unsigned int* __restrict__ packed, int E, int nbins) {
    __shared__ int cur[1024];
    int b = blockIdx.x, t = threadIdx.x;
    for (int i = t; i < nbins; i += 256) cur[i] = tmp[i * NB + b] + boffs[i];
    __syncthreads();
    int chunk = (E + NB - 1) / NB;
    int base = b * chunk;
    int lim = min(base + chunk, E);
    for (int e = base + t; e < lim; e += 256) {
        int d = dst[e];
        int bin = d >> BIN_SHIFT;
        int pos = atomicAdd(&cur[bin], 1);   // LDS atomic
        packed[pos] = ((unsigned int)(d & (BIN_SIZE - 1)) << 20) | (unsigned int)src[e];
    }
}

__global__ __launch_bounds__(256) void bin_fill(
    const unsigned int* __restrict__ packed, const int* __restrict__ tmp,
    const int* __restrict__ boffs,
    int* __restrict__ row_start, int* __restrict__ csr_src, int N, int nbins, int E) {
    __shared__ int cnt[BIN_SIZE];
    __shared__ int pre[BIN_SIZE];
    __shared__ int ex[BIN_SIZE];
    int b = blockIdx.x;
    int t = threadIdx.x;
    int node0 = b << BIN_SHIFT;
    int beg = tmp[b * NB] + boffs[b];
    int end = (b + 1 < nbins) ? (tmp[(b + 1) * NB] + boffs[b + 1]) : E;

    if (t < BIN_SIZE) cnt[t] = 0;
    __syncthreads();
    for (int i = beg + t; i < end; i += 256)
        atomicAdd(&cnt[packed[i] >> 20], 1);
    __syncthreads();
    if (t < BIN_SIZE) pre[t] = cnt[t];
    __syncthreads();
    for (int off = 1; off < BIN_SIZE; off <<= 1) {
        int u = (t < BIN_SIZE && t >= off) ? pre[t - off] : 0;
        __syncthreads();
        if (t < BIN_SIZE) pre[t] += u;
        __syncthreads();
    }
    if (t < BIN_SIZE) {
        ex[t] = pre[t] - cnt[t];
        int node = node0 + t;
        if (node < N) row_start[node] = beg + ex[t];
        cnt[t] = 0;
    }
    if (b == nbins - 1 && t == 0) row_start[N] = E;
    __syncthreads();
    for (int i = beg + t; i < end; i += 256) {
        unsigned int p = packed[i];
        int dl = p >> 20;
        int s = p & 0xFFFFF;
        int ofs = atomicAdd(&cnt[dl], 1);
        csr_src[beg + ex[dl] + ofs] = s;
    }
}

// ------------------------------------------------------------- prep kernel
// blocks [0, castBlocks): x -> xb (bf16) + xq (fp8 e4m3), 16 dims/thread.
// next 128: W1t transpose; next 80: W2t; last 1: zero rows (xq/t2lo/t2hi @ N).

__global__ void cast_prep(const float* __restrict__ x,
                          const float* __restrict__ W1s, const float* __restrict__ W1n,
                          const float* __restrict__ W2s, const float* __restrict__ W2n,
                          unsigned short* __restrict__ xb, unsigned char* __restrict__ xq,
                          unsigned short* __restrict__ W1t, unsigned short* __restrict__ W2t,
                          unsigned short* __restrict__ t2lo, unsigned short* __restrict__ t2hi,
                          int n16, int castBlocks, int N) {
    int blk = blockIdx.x, t = threadIdx.x;
    if (blk < castBlocks) {
        int i = blk * 256 + t;
        if (i >= n16) return;
        const float4* p = (const float4*)x + (size_t)i * 4;
        float4 v0 = p[0], v1 = p[1], v2 = p[2], v3 = p[3];
        float f[16] = {v0.x, v0.y, v0.z, v0.w, v1.x, v1.y, v1.z, v1.w,
                       v2.x, v2.y, v2.z, v2.w, v3.x, v3.y, v3.z, v3.w};
        unsigned short ob[16];
#pragma unroll
        for (int k = 0; k < 16; k++) ob[k] = f2b(f[k]);
        *(float4*)(xb + (size_t)i * 16) = *(float4*)&ob[0];
        *(float4*)(xb + (size_t)i * 16 + 8) = *(float4*)&ob[8];
        unsigned int w[4];
#pragma unroll
        for (int k = 0; k < 4; k++) {
            int u = __builtin_amdgcn_cvt_pk_fp8_f32(f[4 * k + 0], f[4 * k + 1], 0, false);
            u = __builtin_amdgcn_cvt_pk_fp8_f32(f[4 * k + 2], f[4 * k + 3], u, true);
            w[k] = (unsigned int)u;
        }
        *(uint4*)(xq + (size_t)i * 16) = *(uint4*)w;
    } else if (blk < castBlocks + 128) {
        int c = blk - castBlocks;
        float v = (t < 128) ? W1s[(size_t)t * 128 + c] : W1n[(size_t)(t - 128) * 128 + c];
        W1t[(size_t)c * 256 + t] = f2b(v);
    } else if (blk < castBlocks + 208) {
        if (t < 128) {
            int c = blk - castBlocks - 128;
            float v = (c < 40) ? W2s[(size_t)t * 40 + c] : W2n[(size_t)t * 40 + (c - 40)];
            W2t[(size_t)c * 128 + t] = f2b(v);
        }
    } else {
        // zero rows at index N
        if (t < 32) ((unsigned int*)(xq + (size_t)N * 128))[t] = 0u;
        else if (t < 48) ((unsigned int*)(t2lo + (size_t)N * 32))[t - 32] = 0u;
        else if (t < 52) ((unsigned int*)(t2hi + (size_t)N * 8))[t - 48] = 0u;
    }
}

// ------------------------------------------------------- aggregation kernels

// One wave per node over fp8 rows (128 B). Quarter q handles edges e+4q+k
// (k=0..3); lane-in-quarter l owns dims [8l, 8l+8) via uint2. Out-of-range
// slots clamp to zero row N -> every iteration issues 4 gathers/lane.
// csr indices for iteration i+1 are prefetched before iteration i's gathers
// are consumed (clamped addressing makes over-read safe).
__global__ void agg_mean_fp8(const unsigned char* __restrict__ xq,
                             const int* __restrict__ row_start,
                             const int* __restrict__ csr_src,
                             unsigned short* __restrict__ aggb, int N) {
    int wave = (blockIdx.x * blockDim.x + threadIdx.x) >> 6;
    int lane = threadIdx.x & 63;
    if (wave >= N) return;
    int q = lane >> 4;
    int l = lane & 15;
    int beg = row_start[wave], end = row_start[wave + 1];
    const char* xbase = (const char*)xq;
    unsigned loff = (unsigned)l << 3;

    float a[8];
#pragma unroll
    for (int k = 0; k < 8; k++) a[k] = 0.f;

    int s[4];
#pragma unroll
    for (int k = 0; k < 4; k++) {
        int ee = beg + 4 * q + k;
        int idx = csr_src[min(ee, end - 1)];
        s[k] = (ee < end) ? idx : N;              // N = zero row
    }

    for (int e = beg; e < end; e += 16) {
        int eq = e + 4 * q;
        int ns[4];
#pragma unroll
        for (int k = 0; k < 4; k++) {             // prefetch next iteration
            int ee = eq + 16 + k;
            int idx = csr_src[min(ee, end - 1)];
            ns[k] = (ee < end) ? idx : N;
        }
#pragma unroll
        for (int k = 0; k < 4; k++) {
            uint2 v = *(const uint2*)(xbase + (((unsigned)s[k] << 7) + loff));
            f32x2 p0 = __builtin_amdgcn_cvt_pk_f32_fp8(v.x, false);
            f32x2 p1 = __builtin_amdgcn_cvt_pk_f32_fp8(v.x, true);
            f32x2 p2 = __builtin_amdgcn_cvt_pk_f32_fp8(v.y, false);
            f32x2 p3 = __builtin_amdgcn_cvt_pk_f32_fp8(v.y, true);
            a[0] += p0.x; a[1] += p0.y; a[2] += p1.x; a[3] += p1.y;
            a[4] += p2.x; a[5] += p2.y; a[6] += p3.x; a[7] += p3.y;
        }
#pragma unroll
        for (int k = 0; k < 4; k++) s[k] = ns[k];
    }

#pragma unroll
    for (int k = 0; k < 8; k++) {
        a[k] += __shfl_xor(a[k], 16);
        a[k] += __shfl_xor(a[k], 32);
    }
    if (q == 0) {
        float inv = 1.0f / fmaxf((float)(end - beg), 1.0f);
        unsigned int ow[4];
#pragma unroll
        for (int k = 0; k < 4; k++)
            ow[k] = (unsigned int)f2b(a[2 * k] * inv) |
                    ((unsigned int)f2b(a[2 * k + 1] * inv) << 16);
        *(uint4*)((char*)aggb + (((unsigned)wave << 8) + ((unsigned)l << 4))) = *(uint4*)ow;
    }
}

// One wave per node over split bf16 t2. Quarter q: edges e+4q+k; lanes 0-7
// read uint2 from t2lo (64B rows), lanes 8-9 from t2hi (16B rows). Zero rows
// at N make the loop fully predicated (4 gathers/lane every iteration).
// Same one-iteration csr index prefetch as agg_mean_fp8.
__global__ void agg2_add(const unsigned short* __restrict__ t2lo,
                         const unsigned short* __restrict__ t2hi,
                         const int* __restrict__ row_start,
                         const int* __restrict__ csr_src, const float* __restrict__ b2,
                         float* __restrict__ out, int N) {
    int wave = (blockIdx.x * blockDim.x + threadIdx.x) >> 6;
    int lane = threadIdx.x & 63;
    if (wave >= N) return;
    int q = lane >> 4;
    int l = lane & 15;
    int beg = row_start[wave], end = row_start[wave + 1];
    const char* lob = (const char*)t2lo;
    const char* hib = (const char*)t2hi;
    bool isLo = (l < 8);
    bool active = (l < 10);
    unsigned loff = isLo ? ((unsigned)l << 3) : ((unsigned)(l - 8) << 3);

    float a0 = 0.f, a1 = 0.f, a2 = 0.f, a3 = 0.f;

    int s[4];
#pragma unroll
    for (int k = 0; k < 4; k++) {
        int ee = beg + 4 * q + k;
        int idx = csr_src[min(ee, end - 1)];
        s[k] = (ee < end) ? idx : N;              // N = zero row
    }

    for (int e = beg; e < end; e += 16) {
        int eq = e + 4 * q;
        int ns[4];
#pragma unroll
        for (int k = 0; k < 4; k++) {             // prefetch next iteration
            int ee = eq + 16 + k;
            int idx = csr_src[min(ee, end - 1)];
            ns[k] = (ee < end) ? idx : N;
        }
        if (active) {
#pragma unroll
            for (int k = 0; k < 4; k++) {
                uint2 v = isLo ? *(const uint2*)(lob + (((unsigned)s[k] << 6) + loff))
                               : *(const uint2*)(hib + (((unsigned)s[k] << 4) + loff));
                a0 += blo(v.x); a1 += bhi(v.x);
                a2 += blo(v.y); a3 += bhi(v.y);
            }
        }
#pragma unroll
        for (int k = 0; k < 4; k++) s[k] = ns[k];
    }

    a0 += __shfl_xor(a0, 16); a0 += __shfl_xor(a0, 32);
    a1 += __shfl_xor(a1, 16); a1 += __shfl_xor(a1, 32);
    a2 += __shfl_xor(a2, 16); a2 += __shfl_xor(a2, 32);
    a3 += __shfl_xor(a3, 16); a3 += __shfl_xor(a3, 32);
    if (q == 0 && active) {
        float inv = 1.0f / fmaxf((float)(end - beg), 1.0f);
        float4 bb = ((const float4*)b2)[l];
        float4* op = (float4*)((char*)out + ((unsigned)wave * 160u + ((unsigned)l << 4)));
        float4 cur = *op;
        cur.x += a0 * inv + bb.x;
        cur.y += a1 * inv + bb.y;
        cur.z += a2 * inv + bb.z;
        cur.w += a3 * inv + bb.w;
        *op = cur;
    }
}

// --------------------------------------------------------------- fused GEMM
// Phase 1: h1 = relu([xb|aggb] @ W1cat + b1) into LDS (128x136-stride bf16).
// Phase 2: [out_self | t2lo|t2hi] = h1_tile @ W2cat (W2t in LDS, loaded once).

__global__ __launch_bounds__(256) void gemm12_mfma(
    const unsigned short* __restrict__ xb, const unsigned short* __restrict__ aggb,
    const unsigned short* __restrict__ W1t, const unsigned short* __restrict__ W2t,
    const float* __restrict__ b1, float* __restrict__ out,
    unsigned short* __restrict__ t2lo, unsigned short* __restrict__ t2hi, int N) {

    __shared__ unsigned short As[128 * 40];
    __shared__ unsigned short Bs[128 * 40];
    __shared__ unsigned short Hs[128 * 136];   // h1 tile, +8 pad
    __shared__ unsigned short B2[80 * 136];    // W2t resident

    int tid = threadIdx.x;
    int wave = tid >> 6, lane = tid & 63;
    int row0 = blockIdx.x * 128;
    int m = lane & 15, quad = lane >> 4;

    for (int idx = tid; idx < 1280; idx += 256) {
        int r = idx >> 4, seg = idx & 15;
        *(float4*)&B2[r * 136 + seg * 8] = *(const float4*)(W2t + (size_t)r * 128 + seg * 8);
    }

    f32x4 acc[2][8];
#pragma unroll
    for (int i = 0; i < 2; i++)
#pragma unroll
        for (int j = 0; j < 8; j++) acc[i][j] = (f32x4){0.f, 0.f, 0.f, 0.f};

    for (int k0 = 0; k0 < 256; k0 += 32) {
        __syncthreads();
        {
            int r = tid >> 1, kk = (tid & 1) * 16;
            int row = row0 + r;
            float4 v0 = make_float4(0, 0, 0, 0), v1 = v0;
            if (row < N) {
                const unsigned short* s = (k0 < 128)
                    ? (xb + (size_t)row * 128 + k0 + kk)
                    : (aggb + (size_t)row * 128 + (k0 - 128) + kk);
                const float4* p = (const float4*)s;
                v0 = p[0]; v1 = p[1];
            }
            *(float4*)&As[r * 40 + kk] = v0;
            *(float4*)&As[r * 40 + kk + 8] = v1;
            const float4* q2 = (const float4*)(W1t + (size_t)r * 256 + k0 + kk);
            float4 w0 = q2[0], w1 = q2[1];
            *(float4*)&Bs[r * 40 + kk] = w0;
            *(float4*)&Bs[r * 40 + kk + 8] = w1;
        }
        __syncthreads();

        bf16x8 af0 = *(bf16x8*)&As[(wave * 32 + m) * 40 + quad * 8];
        bf16x8 af1 = *(bf16x8*)&As[(wave * 32 + 16 + m) * 40 + quad * 8];
#pragma unroll
        for (int j = 0; j < 8; j++) {
            bf16x8 bfg = *(bf16x8*)&Bs[(j * 16 + m) * 40 + quad * 8];
            acc[0][j] = __builtin_amdgcn_mfma_f32_16x16x32_bf16(af0, bfg, acc[0][j], 0, 0, 0);
            acc[1][j] = __builtin_amdgcn_mfma_f32_16x16x32_bf16(af1, bfg, acc[1][j], 0, 0, 0);
        }
    }

#pragma unroll
    for (int j = 0; j < 8; j++) {
        int col = j * 16 + m;
        float bias = b1[col];
#pragma unroll
        for (int i = 0; i < 2; i++) {
#pragma unroll
            for (int r = 0; r < 4; r++) {
                int rl = wave * 32 + i * 16 + quad * 4 + r;
                Hs[rl * 136 + col] = f2b(fmaxf(acc[i][j][r] + bias, 0.f));
            }
        }
    }
    __syncthreads();

    f32x4 acc2[2][5];
#pragma unroll
    for (int i = 0; i < 2; i++)
#pragma unroll
        for (int j = 0; j < 5; j++) acc2[i][j] = (f32x4){0.f, 0.f, 0.f, 0.f};

#pragma unroll
    for (int k0 = 0; k0 < 128; k0 += 32) {
        bf16x8 af0 = *(bf16x8*)&Hs[(wave * 32 + m) * 136 + k0 + quad * 8];
        bf16x8 af1 = *(bf16x8*)&Hs[(wave * 32 + 16 + m) * 136 + k0 + quad * 8];
#pragma unroll
        for (int j = 0; j < 5; j++) {
            bf16x8 bfg = *(bf16x8*)&B2[(j * 16 + m) * 136 + k0 + quad * 8];
            acc2[0][j] = __builtin_amdgcn_mfma_f32_16x16x32_bf16(af0, bfg, acc2[0][j], 0, 0, 0);
            acc2[1][j] = __builtin_amdgcn_mfma_f32_16x16x32_bf16(af1, bfg, acc2[1][j], 0, 0, 0);
        }
    }

#pragma unroll
    for (int j = 0; j < 5; j++) {
        int col = j * 16 + m;
#pragma unroll
        for (int i = 0; i < 2; i++) {
#pragma unroll
            for (int r = 0; r < 4; r++) {
                int row = row0 + wave * 32 + i * 16 + quad * 4 + r;
                if (row < N) {
                    float v = acc2[i][j][r];
                    if (col < 40) {
                        out[(size_t)row * 40 + col] = v;
                    } else {
                        int td = col - 40;
                        if (td < 32) t2lo[(size_t)row * 32 + td] = f2b(v);
                        else         t2hi[(size_t)row * 8 + (td - 32)] = f2b(v);
                    }
                }
            }
        }
    }
}

// ------------------------------------------------------------------ launch

extern "C" void kernel_launch(void* const* d_in, const int* in_sizes, int n_in,
                              void* d_out, int out_size, void* d_ws, size_t ws_size,
                              hipStream_t stream) {
    const float* x   = (const float*)d_in[0];
    const int*   src = (const int*)d_in[1];
    const int*   dst = (const int*)d_in[2];
    const float* W1s = (const float*)d_in[3];
    const float* W1n = (const float*)d_in[4];
    const float* b1  = (const float*)d_in[5];
    const float* W2s = (const float*)d_in[6];
    const float* W2n = (const float*)d_in[7];
    const float* b2  = (const float*)d_in[8];
    float* out = (float*)d_out;

    int N = in_sizes[0] / 128;
    int E = in_sizes[1];
    int nbins = (N + BIN_SIZE - 1) / BIN_SIZE;   // 782 for N=100000
    int M = nbins * NB;

    char* ws = (char*)d_ws;
    int*            row_start  = (int*)(ws + OFF_ROWSTART);
    int*            hist       = (int*)(ws + OFF_HIST);
    int*            scanned    = (int*)(ws + OFF_SCAN);
    int*            bsums      = (int*)(ws + OFF_BSUMS);
    int*            boffs      = (int*)(ws + OFF_BOFFS);
    unsigned int*   packed     = (unsigned int*)(ws + OFF_PACKED);
    int*            csr_src    = (int*)(ws + OFF_CSR);
    unsigned short* W1t        = (unsigned short*)(ws + OFF_W1T);
    unsigned short* W2t        = (unsigned short*)(ws + OFF_W2T);
    unsigned short* xb         = (unsigned short*)(ws + OFF_XB);
    unsigned char*  xq         = (unsigned char*)(ws + OFF_XQ);
    unsigned short* aggb       = (unsigned short*)(ws + OFF_AGGB);
    unsigned short* t2lo       = (unsigned short*)(ws + OFF_T2LO);
    unsigned short* t2hi       = (unsigned short*)(ws + OFF_T2HI);

    int scanBlocks = (M + 255) / 256;            // == nbins

    hist_local<<<NB, 256, 0, stream>>>(dst, hist, E, nbins);
    scan1<<<scanBlocks, 256, 0, stream>>>(hist, scanned, bsums, M);
    scan2<<<1, 1024, 0, stream>>>(bsums, boffs, scanBlocks);
    scatter_det<<<NB, 256, 0, stream>>>(src, dst, scanned, boffs, packed, E, nbins);
    bin_fill<<<nbins, 256, 0, stream>>>(packed, scanned, boffs, row_start, csr_src, N, nbins, E);

    int n16 = N * 128 / 16;
    int castBlocks = (n16 + 255) / 256;
    cast_prep<<<castBlocks + 128 + 80 + 1, 256, 0, stream>>>(
        x, W1s, W1n, W2s, W2n, xb, xq, W1t, W2t, t2lo, t2hi, n16, castBlocks, N);

    int aggBlocks = (N * 64 + 255) / 256;
    agg_mean_fp8<<<aggBlocks, 256, 0, stream>>>(xq, row_start, csr_src, aggb, N);
    gemm12_mfma<<<(N + 127) / 128, 256, 0, stream>>>(xb, aggb, W1t, W2t, b1, out, t2lo, t2hi, N);
    agg2_add<<<aggBlocks, 256, 0, stream>>>(t2lo, t2hi, row_start, csr_src, b2, out, N);
}

// Round 5
// 273.468 us; speedup vs baseline: 2.4662x; 1.0493x over previous
//
#include <hip/hip_runtime.h>

// GraphSAGE 2-layer forward on MI355X.
// Round 15: MLP (memory-level-parallelism) restructure of both gather
// kernels. r14 post-mortem: csr prefetch added VALU without cutting stalls
// (44.5->46.9us) -> reverted. agg kernels are latency-bound (VALU ~55%,
// HBM ~31%). New structure: wave = 2 nodes (32-lane half each); 2 groups of
// 16 lanes interleave edges e+2k+g, k=0..7 -> 16-edge window per node and
// 8 gathers/lane in flight (2x r10). Iterations/wave = max(ceil(d/16)) over
// the node pair (~1.61 vs 2x1.43 separate); reduce is 1 shuffle stage (xor
// 16); wave count halves. Also: cast_prep merged into hist_local (block-
// range dispatch) -- independent work, saves a launch and overlaps BW-heavy
// cast with atomic-heavy hist.
//   agg_mean: fp8 rows 128B, 16 lanes x uint2 per edge.
//   agg2:     split bf16 t2 (t2lo 64B / t2hi 16B rows), 10 lanes per edge.
//   Both: predicated full-issue loop via zero row at index N.
// CSR: deterministic counting sort. GEMM: fused gemm12 (h1 tile in LDS).

typedef __attribute__((ext_vector_type(8))) short bf16x8;
typedef __attribute__((ext_vector_type(4))) float f32x4;
typedef __attribute__((ext_vector_type(2))) float f32x2;

#define BIN_SHIFT 7
#define BIN_SIZE  128
#define NB        256          // scatter blocks (= scan block size!)

#define OFF_ROWSTART (1ull << 20)   // 400 KB
#define OFF_HIST     (2ull << 20)   // 800 KB  hist[bin*NB + blk]
#define OFF_SCAN     (3ull << 20)   // 800 KB  block-local exclusive prefix
#define OFF_BSUMS    (4ull << 20)
#define OFF_BOFFS    ((4ull << 20) + (64ull << 10))
#define OFF_PACKED   (5ull << 20)   // 6.4 MB
#define OFF_CSR      (12ull << 20)  // 6.4 MB
#define OFF_W1T      (19ull << 20)  // 64 KB
#define OFF_W2T      (20ull << 20)  // 20 KB
#define OFF_XB       (21ull << 20)  // 25.6 MB bf16 (gemm12 self-term)
#define OFF_XQ       (47ull << 20)  // 12.8 MB + zero row (fp8, N+1 rows)
#define OFF_AGGB     (61ull << 20)  // 25.6 MB bf16
#define OFF_T2LO     (87ull << 20)  // 6.4 MB + zero row (32 bf16/row)
#define OFF_T2HI     (94ull << 20)  // 1.6 MB + zero row (8 bf16/row)

static __device__ __forceinline__ unsigned short f2b(float f) {
    unsigned int u = __float_as_uint(f);
    u += 0x7fffu + ((u >> 16) & 1u);   // round-to-nearest-even
    return (unsigned short)(u >> 16);
}
static __device__ __forceinline__ float blo(unsigned int v) { return __uint_as_float(v << 16); }
static __device__ __forceinline__ float bhi(unsigned int v) { return __uint_as_float(v & 0xffff0000u); }

// --------------------------------------- merged prep: cast_prep + hist_local
// blocks [0, castBlocks): x -> xb (bf16) + xq (fp8 e4m3), 16 dims/thread.
// next 128: W1t transpose; next 80: W2t; next 1: zero rows.
// blocks [castPlus, castPlus+NB): dst histogram into hist[bin*NB + blk].

__global__ __launch_bounds__(256) void cast_hist(
    const float* __restrict__ x,
    const float* __restrict__ W1s, const float* __restrict__ W1n,
    const float* __restrict__ W2s, const float* __restrict__ W2n,
    unsigned short* __restrict__ xb, unsigned char* __restrict__ xq,
    unsigned short* __restrict__ W1t, unsigned short* __restrict__ W2t,
    unsigned short* __restrict__ t2lo, unsigned short* __restrict__ t2hi,
    const int* __restrict__ dst, int* __restrict__ hist,
    int n16, int castBlocks, int castPlus, int N, int E, int nbins) {
    __shared__ int h[1024];
    int blk = blockIdx.x, t = threadIdx.x;
    if (blk >= castPlus) {
        // ---- histogram part
        int b = blk - castPlus;
        for (int i = t; i < nbins; i += 256) h[i] = 0;
        __syncthreads();
        int chunk = (E + NB - 1) / NB;
        int base = b * chunk;
        int lim = min(base + chunk, E);
        for (int e = base + t; e < lim; e += 256)
            atomicAdd(&h[dst[e] >> BIN_SHIFT], 1);
        __syncthreads();
        for (int i = t; i < nbins; i += 256)
            hist[i * NB + b] = h[i];
        return;
    }
    if (blk < castBlocks) {
        int i = blk * 256 + t;
        if (i >= n16) return;
        const float4* p = (const float4*)x + (size_t)i * 4;
        float4 v0 = p[0], v1 = p[1], v2 = p[2], v3 = p[3];
        float f[16] = {v0.x, v0.y, v0.z, v0.w, v1.x, v1.y, v1.z, v1.w,
                       v2.x, v2.y, v2.z, v2.w, v3.x, v3.y, v3.z, v3.w};
        unsigned short ob[16];
#pragma unroll
        for (int k = 0; k < 16; k++) ob[k] = f2b(f[k]);
        *(float4*)(xb + (size_t)i * 16) = *(float4*)&ob[0];
        *(float4*)(xb + (size_t)i * 16 + 8) = *(float4*)&ob[8];
        unsigned int w[4];
#pragma unroll
        for (int k = 0; k < 4; k++) {
            int u = __builtin_amdgcn_cvt_pk_fp8_f32(f[4 * k + 0], f[4 * k + 1], 0, false);
            u = __builtin_amdgcn_cvt_pk_fp8_f32(f[4 * k + 2], f[4 * k + 3], u, true);
            w[k] = (unsigned int)u;
        }
        *(uint4*)(xq + (size_t)i * 16) = *(uint4*)w;
    } else if (blk < castBlocks + 128) {
        int c = blk - castBlocks;
        float v = (t < 128) ? W1s[(size_t)t * 128 + c] : W1n[(size_t)(t - 128) * 128 + c];
        W1t[(size_t)c * 256 + t] = f2b(v);
    } else if (blk < castBlocks + 208) {
        if (t < 128) {
            int c = blk - castBlocks - 128;
            float v = (c < 40) ? W2s[(size_t)t * 40 + c] : W2n[(size_t)t * 40 + (c - 40)];
            W2t[(size_t)c * 128 + t] = f2b(v);
        }
    } else {
        // zero rows at index N
        if (t < 32) ((unsigned int*)(xq + (size_t)N * 128))[t] = 0u;
        else if (t < 48) ((unsigned int*)(t2lo + (size_t)N * 32))[t - 32] = 0u;
        else if (t < 52) ((unsigned int*)(t2hi + (size_t)N * 8))[t - 48] = 0u;
    }
}

// ------------------------------------------------- CSR via counting sort

__global__ void scan1(const int* __restrict__ in, int* __restrict__ tmp,
                      int* __restrict__ bsums, int M) {
    __shared__ int s[256];
    int t = threadIdx.x;
    int i = blockIdx.x * 256 + t;
    int v = (i < M) ? in[i] : 0;
    s[t] = v;
    __syncthreads();
    for (int off = 1; off < 256; off <<= 1) {
        int u = (t >= off) ? s[t - off] : 0;
        __syncthreads();
        s[t] += u;
        __syncthreads();
    }
    if (i < M) tmp[i] = s[t] - v;
    if (t == 255) bsums[blockIdx.x] = s[t];
}

__global__ void scan2(const int* __restrict__ bsums, int* __restrict__ boffs, int nb) {
    __shared__ int s[1024];
    int t = threadIdx.x;
    int v = (t < nb) ? bsums[t] : 0;
    s[t] = v;
    __syncthreads();
    for (int off = 1; off < 1024; off <<= 1) {
        int u = (t >= off) ? s[t - off] : 0;
        __syncthreads();
        s[t] += u;
        __syncthreads();
    }
    if (t < nb) boffs[t] = s[t] - v;
}

__global__ __launch_bounds__(256) void scatter_det(
    const int* __restrict__ src, const int* __restrict__ dst,
    const int* __restrict__ tmp, const int* __restrict__ boffs,
    unsigned int* __restrict__ packed, int E, int nbins) {
    __shared__ int cur[1024];
    int b = blockIdx.x, t = threadIdx.x;
    for (int i = t; i < nbins; i += 256) cur[i] = tmp[i * NB + b] + boffs[i];
    __syncthreads();
    int chunk = (E + NB - 1) / NB;
    int base = b * chunk;
    int lim = min(base + chunk, E);
    for (int e = base + t; e < lim; e += 256) {
        int d = dst[e];
        int bin = d >> BIN_SHIFT;
        int pos = atomicAdd(&cur[bin], 1);   // LDS atomic
        packed[pos] = ((unsigned int)(d & (BIN_SIZE - 1)) << 20) | (unsigned int)src[e];
    }
}

__global__ __launch_bounds__(256) void bin_fill(
    const unsigned int* __restrict__ packed, const int* __restrict__ tmp,
    const int* __restrict__ boffs,
    int* __restrict__ row_start, int* __restrict__ csr_src, int N, int nbins, int E) {
    __shared__ int cnt[BIN_SIZE];
    __shared__ int pre[BIN_SIZE];
    __shared__ int ex[BIN_SIZE];
    int b = blockIdx.x;
    int t = threadIdx.x;
    int node0 = b << BIN_SHIFT;
    int beg = tmp[b * NB] + boffs[b];
    int end = (b + 1 < nbins) ? (tmp[(b + 1) * NB] + boffs[b + 1]) : E;

    if (t < BIN_SIZE) cnt[t] = 0;
    __syncthreads();
    for (int i = beg + t; i < end; i += 256)
        atomicAdd(&cnt[packed[i] >> 20], 1);
    __syncthreads();
    if (t < BIN_SIZE) pre[t] = cnt[t];
    __syncthreads();
    for (int off = 1; off < BIN_SIZE; off <<= 1) {
        int u = (t < BIN_SIZE && t >= off) ? pre[t - off] : 0;
        __syncthreads();
        if (t < BIN_SIZE) pre[t] += u;
        __syncthreads();
    }
    if (t < BIN_SIZE) {
        ex[t] = pre[t] - cnt[t];
        int node = node0 + t;
        if (node < N) row_start[node] = beg + ex[t];
        cnt[t] = 0;
    }
    if (b == nbins - 1 && t == 0) row_start[N] = E;
    __syncthreads();
    for (int i = beg + t; i < end; i += 256) {
        unsigned int p = packed[i];
        int dl = p >> 20;
        int s = p & 0xFFFFF;
        int ofs = atomicAdd(&cnt[dl], 1);
        csr_src[beg + ex[dl] + ofs] = s;
    }
}

// ------------------------------------------------------- aggregation kernels

// Wave = 2 nodes (32-lane half each). Within a half: group g (16 lanes)
// handles edges e+2k+g, k=0..7 -> 16-edge window per node, 8 gathers/lane
// in flight. Lane-in-group l owns dims [8l, 8l+8) of the 128B fp8 row via
// uint2. Out-of-range slots clamp to zero row N. Reduce = 1 shuffle stage.
__global__ void agg_mean_fp8(const unsigned char* __restrict__ xq,
                             const int* __restrict__ row_start,
                             const int* __restrict__ csr_src,
                             unsigned short* __restrict__ aggb, int N) {
    int wv = (blockIdx.x * blockDim.x + threadIdx.x) >> 6;
    int lane = threadIdx.x & 63;
    if (2 * wv >= N) return;
    int node = 2 * wv + (lane >> 5);
    bool valid = node < N;
    int hl = lane & 31;
    int g = hl >> 4;
    int l = hl & 15;
    int beg = valid ? row_start[node] : 0;
    int end = valid ? row_start[node + 1] : 0;
    const char* xbase = (const char*)xq;
    unsigned loff = (unsigned)l << 3;

    float a[8];
#pragma unroll
    for (int k = 0; k < 8; k++) a[k] = 0.f;

    for (int e = beg; e < end; e += 16) {
        int s[8];
#pragma unroll
        for (int k = 0; k < 8; k++) {
            int ee = e + 2 * k + g;
            int idx = csr_src[min(ee, end - 1)];
            s[k] = (ee < end) ? idx : N;          // N = zero row
        }
#pragma unroll
        for (int k = 0; k < 8; k++) {
            uint2 v = *(const uint2*)(xbase + (((unsigned)s[k] << 7) + loff));
            f32x2 p0 = __builtin_amdgcn_cvt_pk_f32_fp8(v.x, false);
            f32x2 p1 = __builtin_amdgcn_cvt_pk_f32_fp8(v.x, true);
            f32x2 p2 = __builtin_amdgcn_cvt_pk_f32_fp8(v.y, false);
            f32x2 p3 = __builtin_amdgcn_cvt_pk_f32_fp8(v.y, true);
            a[0] += p0.x; a[1] += p0.y; a[2] += p1.x; a[3] += p1.y;
            a[4] += p2.x; a[5] += p2.y; a[6] += p3.x; a[7] += p3.y;
        }
    }

#pragma unroll
    for (int k = 0; k < 8; k++)
        a[k] += __shfl_xor(a[k], 16);          // combine the 2 groups
    if (g == 0 && valid) {
        float inv = 1.0f / fmaxf((float)(end - beg), 1.0f);
        unsigned int ow[4];
#pragma unroll
        for (int k = 0; k < 4; k++)
            ow[k] = (unsigned int)f2b(a[2 * k] * inv) |
                    ((unsigned int)f2b(a[2 * k + 1] * inv) << 16);
        *(uint4*)((char*)aggb + (((unsigned)node << 8) + ((unsigned)l << 4))) = *(uint4*)ow;
    }
}

// Same 2-node/16-edge-window structure over split bf16 t2. Lanes l 0-7 of a
// group read uint2 from t2lo (64B rows), 8-9 from t2hi (16B rows); l 10-15
// idle. 8 gathers/lane in flight. Zero rows at N keep the loop predicated.
__global__ void agg2_add(const unsigned short* __restrict__ t2lo,
                         const unsigned short* __restrict__ t2hi,
                         const int* __restrict__ row_start,
                         const int* __restrict__ csr_src, const float* __restrict__ b2,
                         float* __restrict__ out, int N) {
    int wv = (blockIdx.x * blockDim.x + threadIdx.x) >> 6;
    int lane = threadIdx.x & 63;
    if (2 * wv >= N) return;
    int node = 2 * wv + (lane >> 5);
    bool valid = node < N;
    int hl = lane & 31;
    int g = hl >> 4;
    int l = hl & 15;
    int beg = valid ? row_start[node] : 0;
    int end = valid ? row_start[node + 1] : 0;
    const char* lob = (const char*)t2lo;
    const char* hib = (const char*)t2hi;
    bool isLo = (l < 8);
    bool active = (l < 10);
    unsigned loff = isLo ? ((unsigned)l << 3) : ((unsigned)(l - 8) << 3);

    float a0 = 0.f, a1 = 0.f, a2 = 0.f, a3 = 0.f;

    for (int e = beg; e < end; e += 16) {
        int s[8];
#pragma unroll
        for (int k = 0; k < 8; k++) {
            int ee = e + 2 * k + g;
            int idx = csr_src[min(ee, end - 1)];
            s[k] = (ee < end) ? idx : N;          // N = zero row
        }
        if (active) {
#pragma unroll
            for (int k = 0; k < 8; k++) {
                uint2 v = isLo ? *(const uint2*)(lob + (((unsigned)s[k] << 6) + loff))
                               : *(const uint2*)(hib + (((unsigned)s[k] << 4) + loff));
                a0 += blo(v.x); a1 += bhi(v.x);
                a2 += blo(v.y); a3 += bhi(v.y);
            }
        }
    }

    a0 += __shfl_xor(a0, 16);
    a1 += __shfl_xor(a1, 16);
    a2 += __shfl_xor(a2, 16);
    a3 += __shfl_xor(a3, 16);
    if (g == 0 && active && valid) {
        float inv = 1.0f / fmaxf((float)(end - beg), 1.0f);
        float4 bb = ((const float4*)b2)[l];
        float4* op = (float4*)((char*)out + ((unsigned)node * 160u + ((unsigned)l << 4)));
        float4 cur = *op;
        cur.x += a0 * inv + bb.x;
        cur.y += a1 * inv + bb.y;
        cur.z += a2 * inv + bb.z;
        cur.w += a3 * inv + bb.w;
        *op = cur;
    }
}

// --------------------------------------------------------------- fused GEMM
// Phase 1: h1 = relu([xb|aggb] @ W1cat + b1) into LDS (128x136-stride bf16).
// Phase 2: [out_self | t2lo|t2hi] = h1_tile @ W2cat (W2t in LDS, loaded once).

__global__ __launch_bounds__(256) void gemm12_mfma(
    const unsigned short* __restrict__ xb, const unsigned short* __restrict__ aggb,
    const unsigned short* __restrict__ W1t, const unsigned short* __restrict__ W2t,
    const float* __restrict__ b1, float* __restrict__ out,
    unsigned short* __restrict__ t2lo, unsigned short* __restrict__ t2hi, int N) {

    __shared__ unsigned short As[128 * 40];
    __shared__ unsigned short Bs[128 * 40];
    __shared__ unsigned short Hs[128 * 136];   // h1 tile, +8 pad
    __shared__ unsigned short B2[80 * 136];    // W2t resident

    int tid = threadIdx.x;
    int wave = tid >> 6, lane = tid & 63;
    int row0 = blockIdx.x * 128;
    int m = lane & 15, quad = lane >> 4;

    for (int idx = tid; idx < 1280; idx += 256) {
        int r = idx >> 4, seg = idx & 15;
        *(float4*)&B2[r * 136 + seg * 8] = *(const float4*)(W2t + (size_t)r * 128 + seg * 8);
    }

    f32x4 acc[2][8];
#pragma unroll
    for (int i = 0; i < 2; i++)
#pragma unroll
        for (int j = 0; j < 8; j++) acc[i][j] = (f32x4){0.f, 0.f, 0.f, 0.f};

    for (int k0 = 0; k0 < 256; k0 += 32) {
        __syncthreads();
        {
            int r = tid >> 1, kk = (tid & 1) * 16;
            int row = row0 + r;
            float4 v0 = make_float4(0, 0, 0, 0), v1 = v0;
            if (row < N) {
                const unsigned short* s = (k0 < 128)
                    ? (xb + (size_t)row * 128 + k0 + kk)
                    : (aggb + (size_t)row * 128 + (k0 - 128) + kk);
                const float4* p = (const float4*)s;
                v0 = p[0]; v1 = p[1];
            }
            *(float4*)&As[r * 40 + kk] = v0;
            *(float4*)&As[r * 40 + kk + 8] = v1;
            const float4* q2 = (const float4*)(W1t + (size_t)r * 256 + k0 + kk);
            float4 w0 = q2[0], w1 = q2[1];
            *(float4*)&Bs[r * 40 + kk] = w0;
            *(float4*)&Bs[r * 40 + kk + 8] = w1;
        }
        __syncthreads();

        bf16x8 af0 = *(bf16x8*)&As[(wave * 32 + m) * 40 + quad * 8];
        bf16x8 af1 = *(bf16x8*)&As[(wave * 32 + 16 + m) * 40 + quad * 8];
#pragma unroll
        for (int j = 0; j < 8; j++) {
            bf16x8 bfg = *(bf16x8*)&Bs[(j * 16 + m) * 40 + quad * 8];
            acc[0][j] = __builtin_amdgcn_mfma_f32_16x16x32_bf16(af0, bfg, acc[0][j], 0, 0, 0);
            acc[1][j] = __builtin_amdgcn_mfma_f32_16x16x32_bf16(af1, bfg, acc[1][j], 0, 0, 0);
        }
    }

#pragma unroll
    for (int j = 0; j < 8; j++) {
        int col = j * 16 + m;
        float bias = b1[col];
#pragma unroll
        for (int i = 0; i < 2; i++) {
#pragma unroll
            for (int r = 0; r < 4; r++) {
                int rl = wave * 32 + i * 16 + quad * 4 + r;
                Hs[rl * 136 + col] = f2b(fmaxf(acc[i][j][r] + bias, 0.f));
            }
        }
    }
    __syncthreads();

    f32x4 acc2[2][5];
#pragma unroll
    for (int i = 0; i < 2; i++)
#pragma unroll
        for (int j = 0; j < 5; j++) acc2[i][j] = (f32x4){0.f, 0.f, 0.f, 0.f};

#pragma unroll
    for (int k0 = 0; k0 < 128; k0 += 32) {
        bf16x8 af0 = *(bf16x8*)&Hs[(wave * 32 + m) * 136 + k0 + quad * 8];
        bf16x8 af1 = *(bf16x8*)&Hs[(wave * 32 + 16 + m) * 136 + k0 + quad * 8];
#pragma unroll
        for (int j = 0; j < 5; j++) {
            bf16x8 bfg = *(bf16x8*)&B2[(j * 16 + m) * 136 + k0 + quad * 8];
            acc2[0][j] = __builtin_amdgcn_mfma_f32_16x16x32_bf16(af0, bfg, acc2[0][j], 0, 0, 0);
            acc2[1][j] = __builtin_amdgcn_mfma_f32_16x16x32_bf16(af1, bfg, acc2[1][j], 0, 0, 0);
        }
    }

#pragma unroll
    for (int j = 0; j < 5; j++) {
        int col = j * 16 + m;
#pragma unroll
        for (int i = 0; i < 2; i++) {
#pragma unroll
            for (int r = 0; r < 4; r++) {
                int row = row0 + wave * 32 + i * 16 + quad * 4 + r;
                if (row < N) {
                    float v = acc2[i][j][r];
                    if (col < 40) {
                        out[(size_t)row * 40 + col] = v;
                    } else {
                        int td = col - 40;
                        if (td < 32) t2lo[(size_t)row * 32 + td] = f2b(v);
                        else         t2hi[(size_t)row * 8 + (td - 32)] = f2b(v);
                    }
                }
            }
        }
    }
}

// ------------------------------------------------------------------ launch

extern "C" void kernel_launch(void* const* d_in, const int* in_sizes, int n_in,
                              void* d_out, int out_size, void* d_ws, size_t ws_size,
                              hipStream_t stream) {
    const float* x   = (const float*)d_in[0];
    const int*   src = (const int*)d_in[1];
    const int*   dst = (const int*)d_in[2];
    const float* W1s = (const float*)d_in[3];
    const float* W1n = (const float*)d_in[4];
    const float* b1  = (const float*)d_in[5];
    const float* W2s = (const float*)d_in[6];
    const float* W2n = (const float*)d_in[7];
    const float* b2  = (const float*)d_in[8];
    float* out = (float*)d_out;

    int N = in_sizes[0] / 128;
    int E = in_sizes[1];
    int nbins = (N + BIN_SIZE - 1) / BIN_SIZE;   // 782 for N=100000
    int M = nbins * NB;

    char* ws = (char*)d_ws;
    int*            row_start  = (int*)(ws + OFF_ROWSTART);
    int*            hist       = (int*)(ws + OFF_HIST);
    int*            scanned    = (int*)(ws + OFF_SCAN);
    int*            bsums      = (int*)(ws + OFF_BSUMS);
    int*            boffs      = (int*)(ws + OFF_BOFFS);
    unsigned int*   packed     = (unsigned int*)(ws + OFF_PACKED);
    int*            csr_src    = (int*)(ws + OFF_CSR);
    unsigned short* W1t        = (unsigned short*)(ws + OFF_W1T);
    unsigned short* W2t        = (unsigned short*)(ws + OFF_W2T);
    unsigned short* xb         = (unsigned short*)(ws + OFF_XB);
    unsigned char*  xq         = (unsigned char*)(ws + OFF_XQ);
    unsigned short* aggb       = (unsigned short*)(ws + OFF_AGGB);
    unsigned short* t2lo       = (unsigned short*)(ws + OFF_T2LO);
    unsigned short* t2hi       = (unsigned short*)(ws + OFF_T2HI);

    int scanBlocks = (M + 255) / 256;            // == nbins

    int n16 = N * 128 / 16;
    int castBlocks = (n16 + 255) / 256;
    int castPlus = castBlocks + 128 + 80 + 1;

    cast_hist<<<castPlus + NB, 256, 0, stream>>>(
        x, W1s, W1n, W2s, W2n, xb, xq, W1t, W2t, t2lo, t2hi,
        dst, hist, n16, castBlocks, castPlus, N, E, nbins);
    scan1<<<scanBlocks, 256, 0, stream>>>(hist, scanned, bsums, M);
    scan2<<<1, 1024, 0, stream>>>(bsums, boffs, scanBlocks);
    scatter_det<<<NB, 256, 0, stream>>>(src, dst, scanned, boffs, packed, E, nbins);
    bin_fill<<<nbins, 256, 0, stream>>>(packed, scanned, boffs, row_start, csr_src, N, nbins, E);

    int nodePairs = (N + 1) / 2;
    int aggBlocks = (nodePairs * 64 + 255) / 256;
    agg_mean_fp8<<<aggBlocks, 256, 0, stream>>>(xq, row_start, csr_src, aggb, N);
    gemm12_mfma<<<(N + 127) / 128, 256, 0, stream>>>(xb, aggb, W1t, W2t, b1, out, t2lo, t2hi, N);
    agg2_add<<<aggBlocks, 256, 0, stream>>>(t2lo, t2hi, row_start, csr_src, b2, out, N);
}